// Round 1
// baseline (992.423 us; speedup 1.0000x reference)
//
#include <hip/hip_runtime.h>
#include <math.h>

// Shapes (fixed by the benchmark)
#define BB 128      // batch
#define TT 20       // time steps
#define EE 512      // embed dim (== K)
#define HH 512      // hidden dim (== K)
#define VV 10000    // vocab
#define G4 2048     // 4*H

// ---------------------------------------------------------------------------
// Kernel 1: gather inputs X[t*B+b][e] = t==0 ? features[b][e]
//                                              : embed_w[captions[b][t-1]][e]
// ---------------------------------------------------------------------------
__global__ __launch_bounds__(128) void gather_x(
    const float* __restrict__ features,
    const int* __restrict__ captions,
    const float* __restrict__ embed_w,
    float* __restrict__ X)
{
    const int r = blockIdx.x;          // 0..2559, r = t*128 + b
    const int t = r >> 7;
    const int b = r & 127;
    const float* src;
    if (t == 0) {
        src = features + (size_t)b * EE;
    } else {
        const int idx = captions[b * TT + (t - 1)];
        src = embed_w + (size_t)idx * EE;
    }
    // 512 floats = 128 float4; one per thread
    float4 v = ((const float4*)src)[threadIdx.x];
    ((float4*)(X + (size_t)r * EE))[threadIdx.x] = v;
}

// ---------------------------------------------------------------------------
// Kernel 2: generic fp32 NT GEMM:  C[M,N] = A[M,512] @ Bm[N,512]^T + bias
// BM=64, BN=64, BK=32, 256 threads, 4x4 micro-tile.
// M must be a multiple of 64 (2560 ok). N guarded.
// ---------------------------------------------------------------------------
__global__ __launch_bounds__(256) void gemm_nt_bias(
    const float* __restrict__ A,     // [M, 512] row-major
    const float* __restrict__ Bm,    // [N, 512] row-major
    const float* __restrict__ bias0, // [N] or null
    const float* __restrict__ bias1, // [N] or null
    float* __restrict__ C,           // [M, N]
    int M, int N)
{
    __shared__ alignas(16) float AsT[32][68];  // [k][m], padded for alignment+banks
    __shared__ alignas(16) float BsT[32][68];  // [k][n]

    const int m0 = blockIdx.y * 64;
    const int n0 = blockIdx.x * 64;
    const int tid = threadIdx.x;
    const int ty = tid >> 4;    // 0..15 -> rows
    const int tx = tid & 15;    // 0..15 -> cols

    const int lrow = tid >> 2;        // 0..63
    const int lk   = (tid & 3) * 8;   // 0,8,16,24

    float acc[4][4] = {};

    for (int k0 = 0; k0 < 512; k0 += 32) {
        // --- A tile: rows m0..m0+63, k = k0..k0+31 (coalesced), store transposed
        {
            const float4* src = (const float4*)(A + (size_t)(m0 + lrow) * 512 + k0 + lk);
            float4 v0 = src[0];
            float4 v1 = src[1];
            AsT[lk + 0][lrow] = v0.x; AsT[lk + 1][lrow] = v0.y;
            AsT[lk + 2][lrow] = v0.z; AsT[lk + 3][lrow] = v0.w;
            AsT[lk + 4][lrow] = v1.x; AsT[lk + 5][lrow] = v1.y;
            AsT[lk + 6][lrow] = v1.z; AsT[lk + 7][lrow] = v1.w;
        }
        // --- B tile: rows n0..n0+63 of Bm (guarded), store transposed
        {
            const int n = n0 + lrow;
            float4 v0 = make_float4(0.f, 0.f, 0.f, 0.f);
            float4 v1 = make_float4(0.f, 0.f, 0.f, 0.f);
            if (n < N) {
                const float4* src = (const float4*)(Bm + (size_t)n * 512 + k0 + lk);
                v0 = src[0];
                v1 = src[1];
            }
            BsT[lk + 0][lrow] = v0.x; BsT[lk + 1][lrow] = v0.y;
            BsT[lk + 2][lrow] = v0.z; BsT[lk + 3][lrow] = v0.w;
            BsT[lk + 4][lrow] = v1.x; BsT[lk + 5][lrow] = v1.y;
            BsT[lk + 6][lrow] = v1.z; BsT[lk + 7][lrow] = v1.w;
        }
        __syncthreads();

        #pragma unroll
        for (int k = 0; k < 32; ++k) {
            float4 a = *(const float4*)&AsT[k][ty * 4];
            float4 b = *(const float4*)&BsT[k][tx * 4];
            acc[0][0] += a.x * b.x; acc[0][1] += a.x * b.y; acc[0][2] += a.x * b.z; acc[0][3] += a.x * b.w;
            acc[1][0] += a.y * b.x; acc[1][1] += a.y * b.y; acc[1][2] += a.y * b.z; acc[1][3] += a.y * b.w;
            acc[2][0] += a.z * b.x; acc[2][1] += a.z * b.y; acc[2][2] += a.z * b.z; acc[2][3] += a.z * b.w;
            acc[3][0] += a.w * b.x; acc[3][1] += a.w * b.y; acc[3][2] += a.w * b.z; acc[3][3] += a.w * b.w;
        }
        __syncthreads();
    }

    // --- epilogue: bias + store
    float bn[4];
    #pragma unroll
    for (int j = 0; j < 4; ++j) {
        const int n = n0 + tx * 4 + j;
        float bv = 0.f;
        if (n < N) {
            if (bias0) bv += bias0[n];
            if (bias1) bv += bias1[n];
        }
        bn[j] = bv;
    }
    if (n0 + 64 <= N) {
        #pragma unroll
        for (int i = 0; i < 4; ++i) {
            const int m = m0 + ty * 4 + i;
            float4 v = make_float4(acc[i][0] + bn[0], acc[i][1] + bn[1],
                                   acc[i][2] + bn[2], acc[i][3] + bn[3]);
            *(float4*)(C + (size_t)m * N + n0 + tx * 4) = v;
        }
    } else {
        #pragma unroll
        for (int i = 0; i < 4; ++i) {
            const int m = m0 + ty * 4 + i;
            #pragma unroll
            for (int j = 0; j < 4; ++j) {
                const int n = n0 + tx * 4 + j;
                if (n < N) C[(size_t)m * N + n] = acc[i][j] + bn[j];
            }
        }
    }
}

// ---------------------------------------------------------------------------
// Kernel 3: one LSTM step, fused gates-GEMM + elementwise update.
// gates[b][g*512+n] = Xp[t*B+b][g*512+n] + sum_k hprev[b][k]*W_hh[g*512+n][k]
// Block tile: 32 b  x 16 n x 4 gates. Grid: (32 n-tiles, 4 b-tiles).
// Thread (tr,tc): b = b0+tr*2+{0,1}, n = n0+tc, all 4 gates. 256 threads.
// ---------------------------------------------------------------------------
__global__ __launch_bounds__(256) void lstm_step(
    const float* __restrict__ hprev,  // [128, 512]
    const float* __restrict__ Xp,     // [T*B, 2048]
    const float* __restrict__ W_hh,   // [2048, 512]
    const float* __restrict__ c0,     // [128, 512]
    float* __restrict__ cbuf,         // [128, 512]
    float* __restrict__ Hout,         // [T*B, 512] (rows t*B.. written)
    int t)
{
    __shared__ alignas(16) float AsT[32][34];  // [k][b_local]  (float2-aligned)
    __shared__ alignas(16) float BsT[32][68];  // [k][c] c = nn*4+g (float4-aligned)

    const int n0 = blockIdx.x * 16;
    const int b0 = blockIdx.y * 32;
    const int tid = threadIdx.x;
    const int tr = tid >> 4;   // 0..15
    const int tc = tid & 15;   // 0..15

    float acc[2][4] = {};

    for (int k0 = 0; k0 < 512; k0 += 32) {
        // A tile: 32 rows x 32 k = 1024 floats; 1 float4 per thread
        {
            const int lrow = tid >> 3;          // 0..31
            const int lk   = (tid & 7) * 4;     // 0..28
            float4 v = *(const float4*)(hprev + (size_t)(b0 + lrow) * 512 + k0 + lk);
            AsT[lk + 0][lrow] = v.x; AsT[lk + 1][lrow] = v.y;
            AsT[lk + 2][lrow] = v.z; AsT[lk + 3][lrow] = v.w;
        }
        // B tile: 64 cols (c = nn*4+g) x 32 k = 2048 floats; 2 float4 per thread
        {
            const int c  = tid >> 2;            // 0..63
            const int lk = (tid & 3) * 8;       // 0,8,16,24
            const int g  = c & 3;
            const int nn = c >> 2;
            const float* src = W_hh + (size_t)(g * 512 + n0 + nn) * 512 + k0 + lk;
            float4 v0 = *(const float4*)(src);
            float4 v1 = *(const float4*)(src + 4);
            BsT[lk + 0][c] = v0.x; BsT[lk + 1][c] = v0.y;
            BsT[lk + 2][c] = v0.z; BsT[lk + 3][c] = v0.w;
            BsT[lk + 4][c] = v1.x; BsT[lk + 5][c] = v1.y;
            BsT[lk + 6][c] = v1.z; BsT[lk + 7][c] = v1.w;
        }
        __syncthreads();

        #pragma unroll
        for (int k = 0; k < 32; ++k) {
            float2 a = *(const float2*)&AsT[k][tr * 2];
            float4 b = *(const float4*)&BsT[k][tc * 4];
            acc[0][0] += a.x * b.x; acc[0][1] += a.x * b.y;
            acc[0][2] += a.x * b.z; acc[0][3] += a.x * b.w;
            acc[1][0] += a.y * b.x; acc[1][1] += a.y * b.y;
            acc[1][2] += a.y * b.z; acc[1][3] += a.y * b.w;
        }
        __syncthreads();
    }

    const int n = n0 + tc;
    #pragma unroll
    for (int j = 0; j < 2; ++j) {
        const int b = b0 + tr * 2 + j;
        const size_t gr = (size_t)(t * BB + b);
        const float* xr = Xp + gr * G4;
        const float gi = acc[j][0] + xr[0 * 512 + n];
        const float gf = acc[j][1] + xr[1 * 512 + n];
        const float gg = acc[j][2] + xr[2 * 512 + n];
        const float go = acc[j][3] + xr[3 * 512 + n];
        const float iv = 1.f / (1.f + expf(-gi));
        const float fv = 1.f / (1.f + expf(-gf));
        const float gv = tanhf(gg);
        const float ov = 1.f / (1.f + expf(-go));
        const float cold = (t == 0) ? c0[(size_t)b * 512 + n]
                                    : cbuf[(size_t)b * 512 + n];
        const float cn = fv * cold + iv * gv;
        cbuf[(size_t)b * 512 + n] = cn;
        Hout[gr * 512 + n] = ov * tanhf(cn);
    }
}

// ---------------------------------------------------------------------------
extern "C" void kernel_launch(void* const* d_in, const int* in_sizes, int n_in,
                              void* d_out, int out_size, void* d_ws, size_t ws_size,
                              hipStream_t stream)
{
    const float* features = (const float*)d_in[0];
    const int*   captions = (const int*)d_in[1];
    const float* h0       = (const float*)d_in[2];
    const float* c0       = (const float*)d_in[3];
    const float* embed_w  = (const float*)d_in[4];
    const float* W_ih     = (const float*)d_in[5];
    const float* W_hh     = (const float*)d_in[6];
    const float* b_ih     = (const float*)d_in[7];
    const float* b_hh     = (const float*)d_in[8];
    const float* W_lin    = (const float*)d_in[9];
    const float* b_lin    = (const float*)d_in[10];
    float* out = (float*)d_out;

    // workspace layout (floats)
    float* X  = (float*)d_ws;                      // 2560*512
    float* Xp = X  + (size_t)2560 * 512;           // 2560*2048
    float* Hb = Xp + (size_t)2560 * 2048;          // 2560*512
    float* cb = Hb + (size_t)2560 * 512;           // 128*512

    // 1) gather inputs
    gather_x<<<dim3(TT * BB), dim3(128), 0, stream>>>(features, captions, embed_w, X);

    // 2) batched input projection: Xp = X @ W_ih^T + b_ih + b_hh
    gemm_nt_bias<<<dim3(G4 / 64, (TT * BB) / 64), dim3(256), 0, stream>>>(
        X, W_ih, b_ih, b_hh, Xp, TT * BB, G4);

    // 3) sequential LSTM steps (only h @ W_hh^T is sequential)
    for (int t = 0; t < TT; ++t) {
        const float* hp = (t == 0) ? h0 : (Hb + (size_t)(t - 1) * BB * HH);
        lstm_step<<<dim3(HH / 16, BB / 32), dim3(256), 0, stream>>>(
            hp, Xp, W_hh, c0, cb, Hb, t);
    }

    // 4) batched output projection: out = H @ W_lin^T + b_lin
    gemm_nt_bias<<<dim3((VV + 63) / 64, (TT * BB) / 64), dim3(256), 0, stream>>>(
        Hb, W_lin, b_lin, nullptr, out, TT * BB, VV);
}